// Round 13
// baseline (275.457 us; speedup 1.0000x reference)
//
#include <hip/hip_runtime.h>
#include <math.h>

// Problem constants (B=8, S=2048, D=512)
#define B_ 8
#define S_ 2048
#define D_ 512
#define KTOP 204                      // int(2048*0.1)
#define QK_SCALE 0.044194173824159216f // 1/sqrt(512)

typedef short bfrag8 __attribute__((ext_vector_type(8)));  // 8 bf16 (4 VGPRs)
typedef float facc4 __attribute__((ext_vector_type(4)));   // MFMA accumulator

// ---------- helpers ----------
__device__ __forceinline__ unsigned short f2bf(float f) {
  unsigned u = __float_as_uint(f);
  u += 0x7FFFu + ((u >> 16) & 1);   // RNE
  return (unsigned short)(u >> 16);
}

// order-preserving map: descending float order == descending uint order
__device__ __forceinline__ unsigned fkey(float f) {
  unsigned b = __float_as_uint(f);
  return (b & 0x80000000u) ? ~b : (b | 0x80000000u);
}
__device__ __forceinline__ float keyfloat(unsigned k) {
  unsigned b = (k & 0x80000000u) ? (k & 0x7FFFFFFFu) : ~k;
  return __uint_as_float(b);
}

__device__ __forceinline__ void load16(const unsigned short* g, unsigned short* l) {
  __builtin_amdgcn_global_load_lds(
      (const __attribute__((address_space(1))) void*)g,
      (__attribute__((address_space(3))) void*)l, 16, 0, 0);
}

// ---------- fused prep: {Q,K fp32->bf16} + {V -> VT bf16 transpose} (R13) ----------
__global__ __launch_bounds__(256) void prep(const float* __restrict__ Q,
                                            const float* __restrict__ K,
                                            const float* __restrict__ V,
                                            unsigned short* __restrict__ Qb,
                                            unsigned short* __restrict__ Kb,
                                            unsigned short* __restrict__ VT) {
  __shared__ float tile[32][33];
  const unsigned b = blockIdx.x;
  if (b < 16384u) {
    const float* in = (b < 8192u) ? Q : K;
    unsigned short* out = (b < 8192u) ? Qb : Kb;
    const int i = (int)((b & 8191u) * 1024u + threadIdx.x * 4u);
    float4 v = *(const float4*)(in + i);
    ushort4 o;
    o.x = f2bf(v.x); o.y = f2bf(v.y); o.z = f2bf(v.z); o.w = f2bf(v.w);
    *(ushort4*)(out + i) = o;
  } else {
    const unsigned t = b - 16384u;
    const int d0 = (int)(t & 15u) * 32;          // 16 d-tiles
    const int k0 = (int)((t >> 4) & 63u) * 32;   // 64 k-tiles
    const int bz = (int)(t >> 10);               // 8 batches
    const float* Vb = V + (size_t)bz * S_ * D_;
    unsigned short* VTb = VT + (size_t)bz * D_ * S_;
    const int c = threadIdx.x & 31, r = threadIdx.x >> 5;
#pragma unroll
    for (int rr = 0; rr < 32; rr += 8)
      tile[r + rr][c] = Vb[(size_t)(k0 + r + rr) * D_ + d0 + c];
    __syncthreads();
#pragma unroll
    for (int rr = 0; rr < 32; rr += 8)
      VTb[(size_t)(d0 + r + rr) * S_ + k0 + c] = f2bf(tile[c][r + rr]);
  }
}

// ==================== R14: 256-squared 8-phase gemm_qk ====================
// The 128^2/2-phase structure plateaued at 58-62us / MfmaUtil 22% across three
// schedules and two MFMA shapes (R8-R13) — the documented m97-structure ceiling.
// This is the guide's verified escape (m201-style), adapted:
//  - tile 256x256, BK=64, 512 threads = 8 waves (2M x 4N), 128x64 out/wave
//  - LDS 128KB: smA[2]/smB[2], each 256x64 bf16 K-tile, double-buffered
//  - staging/swizzle = R9's PROVEN conflict-free pattern at half-tile (128x64)
//    granularity: global source chunk (c^(r&7)), linear global_load_lds dest,
//    ds_read slot ((kc*4+quad)^(l15&7))
//  - per K-tile, 4 phases; phase q: {ds-read A-frags m=2q,2q+1 (+ all 8 B-frags
//    in ph0 -> 12-read phase); stage ONE half-tile (2 loads); s_barrier;
//    lgkmcnt(0); setprio(1); 16 MFMA; setprio(0); s_barrier}
//  - stage schedule (hazard-checked): A-halves of tile t+1 at t/ph0,ph1
//    (their buffer's A-reads finished at t-1/ph3); B-halves of tile t+2 at
//    t/ph2,ph3 (B of tile t is fully read in t/ph0, so its region is WAR-safe)
//  - counted vmcnt(4) ONCE per K-tile (end of ph3): the 2 newest half-tiles
//    (B of t+2) stay in flight across the barrier; everything tile t+1 needs
//    is forced complete. Last two tiles drain with vmcnt(0).
// Accumulation order per output element identical to R9 (tile-major, k-chunk
// inner) -> bit-identical scores.

__device__ __forceinline__ void stage_half(const unsigned short* M, int ld, int k0,
                                           int tid, unsigned short* dst) {
  // stages 128 rows x 64 cols of M (rows = M's first 128 rows) into dst.
  // 512 threads: r = tid>>3 (0..63), chunk c = tid&7; 2 sweeps of 64 rows.
  // LDS image: row-major [128][64], row r chunk s holds global chunk s^(r&7).
  // Per-wave dest is linear (wave w covers rows 8w..8w+7 = 1KB): global_load_lds ok.
  const int w = tid >> 6;
  const int r = tid >> 3;
  const int c = tid & 7;
  const unsigned short* src = M + (size_t)r * ld + k0 + ((c ^ (r & 7)) * 8);
  unsigned short* wdst = dst + w * 512;
  load16(src, wdst);
  load16(src + (size_t)64 * ld, wdst + 4096);
}

// one phase: read 2 A-frags (m-frags MF0, MF0+1), stage statement, barrier,
// lgkm wait, prio-wrapped 16 MFMAs. Closing barrier is added by the caller.
#define QK8_PHASE(MF0, ...)                                                    \
  {                                                                            \
    af[0][0] = *(const bfrag8*)(curA + aoff + (MF0) * 1024 + sl0);             \
    af[0][1] = *(const bfrag8*)(curA + aoff + (MF0) * 1024 + sl1);             \
    af[1][0] = *(const bfrag8*)(curA + aoff + ((MF0) + 1) * 1024 + sl0);       \
    af[1][1] = *(const bfrag8*)(curA + aoff + ((MF0) + 1) * 1024 + sl1);       \
    __VA_ARGS__;                                                               \
    __builtin_amdgcn_s_barrier();                                              \
    asm volatile("s_waitcnt lgkmcnt(0)" ::: "memory");                         \
    __builtin_amdgcn_sched_barrier(0);                                         \
    __builtin_amdgcn_s_setprio(1);                                             \
    _Pragma("unroll")                                                          \
    for (int kc = 0; kc < 2; ++kc) {                                           \
      _Pragma("unroll")                                                        \
      for (int mi = 0; mi < 2; ++mi) {                                         \
        _Pragma("unroll")                                                      \
        for (int nf = 0; nf < 4; ++nf)                                         \
          acc[(MF0) + mi][nf] = __builtin_amdgcn_mfma_f32_16x16x32_bf16(       \
              af[mi][kc], bf[nf][kc], acc[(MF0) + mi][nf], 0, 0, 0);           \
      }                                                                        \
    }                                                                          \
    __builtin_amdgcn_s_setprio(0);                                             \
  }

__global__ __launch_bounds__(512) void gemm_qk8(
    const unsigned short* __restrict__ A, int lda, long long astr,
    const unsigned short* __restrict__ Bm, int ldb, long long bstr,
    float* __restrict__ C, int ldc, long long cstr,
    int kdim, float scale) {
  const unsigned j = blockIdx.x + 8u * blockIdx.y + 64u * blockIdx.z;
  const unsigned bz = j & 7u;           // batch == XCD residue
  const unsigned q = j >> 3;            // [0,64)
  const unsigned by = q & 7u;           // m-tile
  const unsigned bx = q >> 3;           // n-tile [0,8)

  __shared__ unsigned short smA[2][256 * 64];   // 64KB
  __shared__ unsigned short smB[2][256 * 64];   // 64KB
  const int tid = threadIdx.x;
  const int wave = tid >> 6, lane = tid & 63;
  const int wm = wave >> 2, wn = wave & 3;      // 2M x 4N wave grid
  const int quad = lane >> 4, l15 = lane & 15;
  const unsigned short* Ab = A + (long long)bz * astr + (size_t)(by * 256) * lda;
  const unsigned short* Bb = Bm + (long long)bz * bstr + (size_t)(bx * 256) * ldb;

  const int aoff = (wm * 128 + l15) * 64;       // wave's A-row base (ushorts)
  const int boff = (wn * 64 + l15) * 64;        // wave's B-row base
  const int sl0 = ((quad) ^ (l15 & 7)) * 8;     // swizzled slot, k-chunk 0
  const int sl1 = ((4 + quad) ^ (l15 & 7)) * 8; // swizzled slot, k-chunk 1

  facc4 acc[8][4];
  const facc4 fzero = {0.f, 0.f, 0.f, 0.f};
#pragma unroll
  for (int mf = 0; mf < 8; ++mf)
#pragma unroll
    for (int nf = 0; nf < 4; ++nf) acc[mf][nf] = fzero;

  const int T = kdim >> 6;   // K-tiles of 64 (8 for K=512); requires T >= 2

  // prologue: tile0 A+B (8 loads/thread... 4 stages x 2) + tile1 B (2 stages)
  stage_half(Ab, lda, 0, tid, smA[0]);
  stage_half(Ab + (size_t)128 * lda, lda, 0, tid, smA[0] + 8192);
  stage_half(Bb, ldb, 0, tid, smB[0]);
  stage_half(Bb + (size_t)128 * ldb, ldb, 0, tid, smB[0] + 8192);
  stage_half(Bb, ldb, 64, tid, smB[1]);
  stage_half(Bb + (size_t)128 * ldb, ldb, 64, tid, smB[1] + 8192);
  asm volatile("s_waitcnt vmcnt(4)" ::: "memory");   // tile0 done; tile1-B in flight
  __builtin_amdgcn_s_barrier();
  __builtin_amdgcn_sched_barrier(0);

  for (int t = 0; t < T; ++t) {
    const unsigned short* curA = smA[t & 1];
    const unsigned short* curB = smB[t & 1];
    unsigned short* nA = smA[(t & 1) ^ 1];   // A of tile t+1
    unsigned short* nB = smB[t & 1];         // B of tile t+2 (same parity as t)
    bfrag8 bf[4][2];
    bfrag8 af[2][2];

    // ---- phase 0: all 8 B-frags + A m=0,1; stage A-half0(t+1) ----
#pragma unroll
    for (int nf = 0; nf < 4; ++nf) {
      bf[nf][0] = *(const bfrag8*)(curB + boff + nf * 1024 + sl0);
      bf[nf][1] = *(const bfrag8*)(curB + boff + nf * 1024 + sl1);
    }
    QK8_PHASE(0, if (t + 1 < T) stage_half(Ab, lda, (t + 1) * 64, tid, nA));
    __builtin_amdgcn_s_barrier();

    // ---- phase 1: A m=2,3; stage A-half1(t+1) ----
    QK8_PHASE(2, if (t + 1 < T)
                   stage_half(Ab + (size_t)128 * lda, lda, (t + 1) * 64, tid, nA + 8192));
    __builtin_amdgcn_s_barrier();

    // ---- phase 2: A m=4,5; stage B-half0(t+2) (B(t) fully read in ph0) ----
    QK8_PHASE(4, if (t + 2 < T) stage_half(Bb, ldb, (t + 2) * 64, tid, nB));
    __builtin_amdgcn_s_barrier();

    // ---- phase 3: A m=6,7; stage B-half1(t+2); counted vmcnt ----
    QK8_PHASE(6, if (t + 2 < T)
                   stage_half(Bb + (size_t)128 * ldb, ldb, (t + 2) * 64, tid, nB + 8192));
    if (t < T - 2) {
      asm volatile("s_waitcnt vmcnt(4)" ::: "memory");  // only B(t+2) stays in flight
    } else {
      asm volatile("s_waitcnt vmcnt(0)" ::: "memory");  // drain for last tiles
    }
    __builtin_amdgcn_s_barrier();
    __builtin_amdgcn_sched_barrier(0);
  }

  float* Cb = C + (long long)bz * cstr;
  const int mg = by * 256 + wm * 128;
  const int ng = bx * 256 + wn * 64;
#pragma unroll
  for (int mf = 0; mf < 8; ++mf)
#pragma unroll
    for (int nf = 0; nf < 4; ++nf)
#pragma unroll
      for (int r = 0; r < 4; ++r)
        Cb[(size_t)(mg + mf * 16 + quad * 4 + r) * ldc + ng + nf * 16 + l15] =
            acc[mf][nf][r] * scale;
}

// ---------- R9 128^2 GEMM (kept for gemm_pv: 256^2 would give only 128 blocks) ----------
__device__ __forceinline__ void stage64(const unsigned short* M, int ld, int k0,
                                        int tid, unsigned short* dst) {
  const int wave = tid >> 6;
  const int row = tid >> 3;                              // 0..31 per sweep
  const int col = ((tid & 7) ^ (row & 7)) * 8;           // swizzled source chunk
  unsigned short* wdst = dst + wave * 512;               // 1KB per wave per sweep
  const unsigned short* src = M + (size_t)row * ld + k0 + col;
#pragma unroll
  for (int s = 0; s < 4; ++s)
    load16(src + (size_t)(s * 32) * ld, wdst + s * 2048);
}

__device__ __forceinline__ void mfma_step64(const unsigned short* sA, const unsigned short* sB,
                                            int mrow, int nrow, int l15, int quad,
                                            facc4 (&acc)[4][4]) {
#pragma unroll
  for (int c = 0; c < 2; ++c) {
    const int slot = ((c * 4 + quad) ^ (l15 & 7)) * 8;   // swizzled read slot
    bfrag8 af[4], bq[4];
#pragma unroll
    for (int i = 0; i < 4; ++i)
      af[i] = *(const bfrag8*)(sA + (mrow + 16 * i + l15) * 64 + slot);
#pragma unroll
    for (int j2 = 0; j2 < 4; ++j2)
      bq[j2] = *(const bfrag8*)(sB + (nrow + 16 * j2 + l15) * 64 + slot);
#pragma unroll
    for (int i = 0; i < 4; ++i)
#pragma unroll
      for (int j2 = 0; j2 < 4; ++j2)
        acc[i][j2] = __builtin_amdgcn_mfma_f32_16x16x32_bf16(af[i], bq[j2], acc[i][j2], 0, 0, 0);
  }
}

// gemm_pv: grid (4,16,8); bz = j&7 (batch pins to XCD, VT[b] 2 MB in L2);
// within XCD, bx fastest so the 4 n-blocks sharing one 512 KB attn A-tile run
// back-to-back on the same XCD (A fetched from HBM once).
__global__ __launch_bounds__(256) void gemm_pv(
    const unsigned short* __restrict__ A, int lda, long long astr,
    const unsigned short* __restrict__ Bm, int ldb, long long bstr,
    float* __restrict__ C, int ldc, long long cstr,
    int kdim, float scale) {
  const unsigned j = blockIdx.x + 4u * blockIdx.y + 64u * blockIdx.z;
  const unsigned bz = j & 7u;           // batch == XCD residue
  const unsigned q = j >> 3;            // [0,64)
  const unsigned bx = q & 3u;           // n-tile (fastest)
  const unsigned by = q >> 2;           // m-tile [0,16)

  __shared__ unsigned short smA[2][128 * 64];
  __shared__ unsigned short smB[2][128 * 64];
  const int tid = threadIdx.x;
  const int wave = tid >> 6, lane = tid & 63;
  const int quad = lane >> 4, l15 = lane & 15;
  const unsigned short* Ab = A + (long long)bz * astr + (size_t)(by * 128) * lda;
  const unsigned short* Bb = Bm + (long long)bz * bstr + (size_t)(bx * 128) * ldb;
  const int mrow = 64 * (wave >> 1);
  const int nrow = 64 * (wave & 1);

  facc4 acc[4][4];
  const facc4 fzero = {0.f, 0.f, 0.f, 0.f};
#pragma unroll
  for (int i = 0; i < 4; ++i)
#pragma unroll
    for (int j2 = 0; j2 < 4; ++j2) acc[i][j2] = fzero;

  stage64(Ab, lda, 0, tid, smA[0]);
  stage64(Bb, ldb, 0, tid, smB[0]);
  __syncthreads();

  for (int k0 = 0; k0 < kdim; k0 += 128) {
    stage64(Ab, lda, k0 + 64, tid, smA[1]);
    stage64(Bb, ldb, k0 + 64, tid, smB[1]);
    mfma_step64(smA[0], smB[0], mrow, nrow, l15, quad, acc);
    __syncthreads();
    if (k0 + 128 < kdim) {
      stage64(Ab, lda, k0 + 128, tid, smA[0]);
      stage64(Bb, ldb, k0 + 128, tid, smB[0]);
    }
    mfma_step64(smA[1], smB[1], mrow, nrow, l15, quad, acc);
    __syncthreads();
  }

  float* Cb = C + (long long)bz * cstr;
  const int mg = by * 128 + mrow;
  const int ng = bx * 128 + nrow;
#pragma unroll
  for (int i = 0; i < 4; ++i)
#pragma unroll
    for (int j2 = 0; j2 < 4; ++j2)
#pragma unroll
      for (int r = 0; r < 4; ++r)
        Cb[(size_t)(mg + 16 * i + quad * 4 + r) * ldc + ng + 16 * j2 + l15] = acc[i][j2][r] * scale;
}

// ---------- 256-bin radix-select step ----------
__device__ __forceinline__ unsigned sel256(const unsigned* bins, int lane,
                                           unsigned krem, unsigned* krem_out) {
  const uint4 b = *(const uint4*)(bins + lane * 4);
  const unsigned s = b.x + b.y + b.z + b.w;
  unsigned t = s;
#pragma unroll
  for (int off = 1; off < 64; off <<= 1) {
    unsigned u = (unsigned)__shfl_down((int)t, off);
    t += (lane + off < 64) ? u : 0u;
  }
  const unsigned texcl = t - s;           // suffix over lanes > lane
  const unsigned c3 = texcl + b.w;        // count(digit >= lane*4+3)
  const unsigned c2 = c3 + b.z;
  const unsigned c1 = c2 + b.y;
  const unsigned c0 = c1 + b.x;
  unsigned pack = 0;                      // nonzero in at most one lane
  if (c0 >= krem && c1 < krem)    pack = ((krem - c1) << 8) | (lane * 4 + 0);
  if (c1 >= krem && c2 < krem)    pack = ((krem - c2) << 8) | (lane * 4 + 1);
  if (c2 >= krem && c3 < krem)    pack = ((krem - c3) << 8) | (lane * 4 + 2);
  if (c3 >= krem && texcl < krem) pack = ((krem - texcl) << 8) | (lane * 4 + 3);
#pragma unroll
  for (int off = 1; off < 64; off <<= 1)
    pack |= (unsigned)__shfl_xor((int)pack, off);
  *krem_out = pack >> 8;
  return pack & 255u;
}

// ---------- per-row exact top-204 + softmax-of-sparse; TWO waves per row (R12) ----------
__global__ __launch_bounds__(256) void topk_softmax(float* __restrict__ scores) {
  __shared__ unsigned binsAll[2][256];    // one 256-bin histogram per row
  __shared__ unsigned xchg[2][4];         // [0,1]=kmax/zsum, [2]=pack/cut, [3]=tc
  const int tid = threadIdx.x;
  const int wave = tid >> 6, lane = tid & 63;
  const int pair = wave >> 1, h = wave & 1;     // pair = row-in-block, h = half
  const long long row = (long long)blockIdx.x * 2 + pair;
  float* srow = scores + row * 2048 + h * 1024;
  unsigned* bins = binsAll[pair];
  unsigned* xch = xchg[pair];

  unsigned k[16];
#pragma unroll
  for (int c = 0; c < 2; ++c) {
    float4 a = *(const float4*)(srow + c * 512 + lane * 8);
    float4 b = *(const float4*)(srow + c * 512 + lane * 8 + 4);
    k[c * 8 + 0] = fkey(a.x); k[c * 8 + 1] = fkey(a.y);
    k[c * 8 + 2] = fkey(a.z); k[c * 8 + 3] = fkey(a.w);
    k[c * 8 + 4] = fkey(b.x); k[c * 8 + 5] = fkey(b.y);
    k[c * 8 + 6] = fkey(b.z); k[c * 8 + 7] = fkey(b.w);
  }

  // zero bins (128 threads/row x uint2) + per-wave kmax -> LDS
  {
    uint2 z; z.x = 0; z.y = 0;
    *(uint2*)(bins + (h * 64 + lane) * 2) = z;
  }
  unsigned kmax = 0;
#pragma unroll
  for (int i = 0; i < 16; ++i) kmax = max(kmax, k[i]);
#pragma unroll
  for (int off = 1; off < 64; off <<= 1)
    kmax = max(kmax, (unsigned)__shfl_xor((int)kmax, off));
  if (lane == 0) xch[h] = kmax;
  __syncthreads();                                       // B1
  kmax = max(xch[0], xch[1]);
  const float m = fmaxf(keyfloat(kmax), 0.f);

  // ---- slot 0: quantile digit t = (key>>16)-0xBF00, count only t in [1,255] ----
#pragma unroll
  for (int i = 0; i < 16; ++i) {
    const int t = (int)(k[i] >> 16) - 0xBF00;
    if (t >= 1) atomicAdd(&bins[min(t, 255)], 1u);
  }
  __syncthreads();                                       // B2
  if (h == 0) {
    unsigned kr;
    const unsigned d = sel256(bins, lane, KTOP, &kr);
    if (lane == 0) xch[2] = (kr << 8) | d;
    asm volatile("s_waitcnt lgkmcnt(0)" ::: "memory");   // order read-before-zero
    uint4 z4; z4.x = 0; z4.y = 0; z4.z = 0; z4.w = 0;
    *(uint4*)(bins + lane * 4) = z4;
  }
  __syncthreads();                                       // B3
  unsigned pack = xch[2];
  const unsigned d1 = pack & 255u;
  unsigned krem = pack >> 8;

  const bool fb = (d1 < 1u || d1 > 254u);                // never for this data
  unsigned prefix, mmask;
  if (!fb) { prefix = (0xBF00u + d1) << 16; mmask = 0xFFFF0000u; }
  else     { prefix = 0u; mmask = 0u; krem = KTOP; }

  // ---- slots 1..4: common = {bits15:8, bits7:0, dummy, dummy}; fb = 4x8-bit radix ----
  for (int s = 1; s <= 4; ++s) {
    const bool active = fb || (s <= 2);
    const int shift = fb ? (32 - 8 * s) : ((s == 1) ? 8 : 0);
    if (active) {
#pragma unroll
      for (int i = 0; i < 16; ++i)
        if ((k[i] & mmask) == prefix) atomicAdd(&bins[(k[i] >> shift) & 255u], 1u);
    }
    __syncthreads();                                     // B4/6/8/10
    if (h == 0 && active) {
      unsigned kr;
      const unsigned d = sel256(bins, lane, krem, &kr);
      if (lane == 0) xch[2] = (kr << 8) | d;
      asm volatile("s_waitcnt lgkmcnt(0)" ::: "memory");
      uint4 z4; z4.x = 0; z4.y = 0; z4.z = 0; z4.w = 0;
      *(uint4*)(bins + lane * 4) = z4;
    }
    __syncthreads();                                     // B5/7/9/11
    if (active) {
      pack = xch[2];
      prefix |= (pack & 255u) << shift;
      krem = pack >> 8;
      mmask |= 0xFFu << shift;
    }
  }
  const unsigned tkey = prefix;

  // ---- tie-break across the two halves: krem lowest-index ties ----
  unsigned tiem = 0;
#pragma unroll
  for (int i = 0; i < 16; ++i)
    if (k[i] == tkey) tiem |= 1u << i;
  unsigned tc = (unsigned)__popc(tiem);
#pragma unroll
  for (int off = 1; off < 64; off <<= 1)
    tc += (unsigned)__shfl_xor((int)tc, off);
  if (h == 0 && lane == 0) xch[3] = tc;
  __syncthreads();                                       // B12
  const unsigned tcA = xch[3];
  const int whichHalf = (krem <= tcA) ? 0 : 1;           // half containing the cut
  if (h == whichHalf) {
    unsigned need = whichHalf ? (krem - tcA) : krem;     // >=1 by construction
    unsigned cutl;
    for (;;) {
      unsigned myidx = 0xFFFFFFFFu;
      if (tiem) {
        int i = __ffs((int)tiem) - 1;
        myidx = (unsigned)(h * 1024) + ((unsigned)(i >> 3)) * 512u +
                (unsigned)lane * 8u + (unsigned)(i & 7);
      }
      unsigned minidx = myidx;
#pragma unroll
      for (int off = 1; off < 64; off <<= 1)
        minidx = min(minidx, (unsigned)__shfl_xor((int)minidx, off));
      if (--need == 0 || minidx == 0xFFFFFFFFu) { cutl = minidx; break; }
      if (myidx == minidx) tiem &= tiem - 1;             // consume in owning lane
    }
    if (lane == 0) xch[2] = cutl;
  }
  __syncthreads();                                       // B13
  const unsigned cut = xch[2];

  // ---- weights + cross-pair Z ----
  const float eqw = __expf(keyfloat(tkey) - m);
  const float base = __expf(-m);
  float zsum = 0.f;
#pragma unroll
  for (int i = 0; i < 16; ++i) {
    const unsigned key = k[i];
    const unsigned idx = (unsigned)(h * 1024) + ((unsigned)(i >> 3)) * 512u +
                         (unsigned)lane * 8u + (unsigned)(i & 7);
    float w;
    if (key > tkey) w = __expf(keyfloat(key) - m);
    else w = (key == tkey && idx <= cut) ? eqw : base;
    zsum += w;
    k[i] = __float_as_uint(w);              // stash unnormalized weight
  }
#pragma unroll
  for (int off = 1; off < 64; off <<= 1) zsum += __shfl_xor(zsum, off);
  if (lane == 0) xch[h] = __float_as_uint(zsum);
  __syncthreads();                                       // B14
  const float Z = __uint_as_float(xch[0]) + __uint_as_float(xch[1]);
  const float invZ = 1.f / Z;

  // attn row (bf16) reuses the front 4KB of this row's 8KB score slot
  unsigned short* arow = (unsigned short*)scores + row * 4096 + h * 1024;
#pragma unroll
  for (int c = 0; c < 2; ++c) {
    union { unsigned short u[8]; int4 v4; } pk;
#pragma unroll
    for (int j = 0; j < 8; ++j)
      pk.u[j] = f2bf(__uint_as_float(k[c * 8 + j]) * invZ);
    *(int4*)(arow + c * 512 + lane * 8) = pk.v4;
  }
}

// ---------- launch ----------
// ws layout (bytes): Qb[0,16MB) Kb[16,32MB) VT[32,48MB) scores/attn[48,176MB)
extern "C" void kernel_launch(void* const* d_in, const int* in_sizes, int n_in,
                              void* d_out, int out_size, void* d_ws, size_t ws_size,
                              hipStream_t stream) {
  const float* Q = (const float*)d_in[0];
  const float* K = (const float*)d_in[1];
  const float* V = (const float*)d_in[2];
  float* out = (float*)d_out;
  char* ws = (char*)d_ws;
  unsigned short* Qb = (unsigned short*)(ws);
  unsigned short* Kb = (unsigned short*)(ws + ((size_t)16 << 20));
  unsigned short* VT = (unsigned short*)(ws + ((size_t)32 << 20));
  float* scores = (float*)(ws + ((size_t)48 << 20));

  // fused convert + transpose: 16384 cvt blocks + 8192 transpose blocks
  prep<<<24576, 256, 0, stream>>>(Q, K, V, Qb, Kb, VT);
  // scores[b][q][k] = sum_d Q[q][d]*K[k][d] * scale ; 256^2 tiles, 8 waves
  gemm_qk8<<<dim3(8, 8, 8), 512, 0, stream>>>(
      Qb, D_, (long long)S_ * D_, Kb, D_, (long long)S_ * D_,
      scores, S_, (long long)S_ * S_, D_, QK_SCALE);
  topk_softmax<<<B_ * S_ / 2, 256, 0, stream>>>(scores);
  // out[b][q][d] = sum_k attn[q][k]*VT[d][k] ; attn row pitch = 4096 bf16 (8KB slots)
  gemm_pv<<<dim3(D_ / 128, S_ / 128, B_), 256, 0, stream>>>(
      (const unsigned short*)scores, 4096, (long long)S_ * 4096,
      VT, S_, (long long)D_ * S_, out, D_, (long long)S_ * D_, S_, 1.0f);
}

// Round 14
// 265.664 us; speedup vs baseline: 1.0369x; 1.0369x over previous
//
#include <hip/hip_runtime.h>
#include <math.h>

// Problem constants (B=8, S=2048, D=512)
#define B_ 8
#define S_ 2048
#define D_ 512
#define KTOP 204                      // int(2048*0.1)
#define QK_SCALE 0.044194173824159216f // 1/sqrt(512)

typedef short bfrag8 __attribute__((ext_vector_type(8)));  // 8 bf16 (4 VGPRs)
typedef float facc4 __attribute__((ext_vector_type(4)));   // MFMA accumulator

// ---------- helpers ----------
__device__ __forceinline__ unsigned short f2bf(float f) {
  unsigned u = __float_as_uint(f);
  u += 0x7FFFu + ((u >> 16) & 1);   // RNE
  return (unsigned short)(u >> 16);
}

// order-preserving map: descending float order == descending uint order
__device__ __forceinline__ unsigned fkey(float f) {
  unsigned b = __float_as_uint(f);
  return (b & 0x80000000u) ? ~b : (b | 0x80000000u);
}
__device__ __forceinline__ float keyfloat(unsigned k) {
  unsigned b = (k & 0x80000000u) ? (k & 0x7FFFFFFFu) : ~k;
  return __uint_as_float(b);
}

__device__ __forceinline__ void load16(const unsigned short* g, unsigned short* l) {
  __builtin_amdgcn_global_load_lds(
      (const __attribute__((address_space(1))) void*)g,
      (__attribute__((address_space(3))) void*)l, 16, 0, 0);
}

// ---------- fp32 -> bf16 convert, Q and K in one launch ----------
__global__ __launch_bounds__(256) void cvt_qk(const float* __restrict__ Q,
                                              const float* __restrict__ K,
                                              unsigned short* __restrict__ Qb,
                                              unsigned short* __restrict__ Kb) {
  const float* in = blockIdx.y ? K : Q;
  unsigned short* out = blockIdx.y ? Kb : Qb;
  int i = (blockIdx.x * 256 + threadIdx.x) * 4;
  float4 v = *(const float4*)(in + i);
  ushort4 o;
  o.x = f2bf(v.x); o.y = f2bf(v.y); o.z = f2bf(v.z); o.w = f2bf(v.w);
  *(ushort4*)(out + i) = o;
}

// ---------- V [b][k][d] fp32 -> VT [b][d][k] bf16 ----------
__global__ __launch_bounds__(256) void transpose_v(const float* __restrict__ V,
                                                   unsigned short* __restrict__ VT) {
  __shared__ float tile[32][33];
  int b = blockIdx.z;
  int d0 = blockIdx.x * 32, k0 = blockIdx.y * 32;
  const float* Vb = V + (size_t)b * S_ * D_;
  unsigned short* VTb = VT + (size_t)b * D_ * S_;
  int c = threadIdx.x & 31, r = threadIdx.x >> 5;
#pragma unroll
  for (int rr = 0; rr < 32; rr += 8)
    tile[r + rr][c] = Vb[(size_t)(k0 + r + rr) * D_ + d0 + c];
  __syncthreads();
#pragma unroll
  for (int rr = 0; rr < 32; rr += 8)
    VTb[(size_t)(d0 + r + rr) * S_ + k0 + c] = f2bf(tile[c][r + rr]);
}

// ---------- GEMM building blocks ----------
// R9 (best measured whole build, total 270.8us): BK=64 double-buffered with a
// true T2 XOR swizzle. At BK=32 (4 slots/row) a swizzle can't spread banks
// (R7 lesson); at BK=64 (8 x 16B slots/row) it reaches all 32 banks.
// Both-sides-or-neither (rule #21): global SOURCE chunk is pre-swizzled
// ((l&7)^(row&7)), LDS dest stays linear (global_load_lds writes base+lane*16),
// ds_read slot applies the same involution ((c*4+quad)^(l15&7)).
// Measured: SQ_LDS_BANK_CONFLICT = 0, gemm_qk ~59us. Consolidation round:
// resubmitted bit-for-bit after R10-R14 structural variants (3-deep counted
// vmcnt, 32x32 MFMA shape, 256^2 8-phase+setprio) all landed within the
// +-4% build-lottery noise band without unlocking MfmaUtil past ~23%.

// stage one 128x64 k-tile of matrix M into LDS buffer dst (wave-uniform base).
// 4 sweeps of 32 rows; lane l covers row (tid>>3), chunk (l&7) pre-swizzled.
__device__ __forceinline__ void stage64(const unsigned short* M, int ld, int k0,
                                        int tid, unsigned short* dst) {
  const int wave = tid >> 6;
  const int row = tid >> 3;                              // 0..31 per sweep
  const int col = ((tid & 7) ^ (row & 7)) * 8;           // swizzled source chunk
  unsigned short* wdst = dst + wave * 512;               // 1KB per wave per sweep
  const unsigned short* src = M + (size_t)row * ld + k0 + col;
#pragma unroll
  for (int s = 0; s < 4; ++s)
    load16(src + (size_t)(s * 32) * ld, wdst + s * 2048);
}

// 32 MFMAs over one 128x64 x 128x64 LDS tile pair (2 k-chunks of 32).
__device__ __forceinline__ void mfma_step64(const unsigned short* sA, const unsigned short* sB,
                                            int mrow, int nrow, int l15, int quad,
                                            facc4 (&acc)[4][4]) {
#pragma unroll
  for (int c = 0; c < 2; ++c) {
    const int slot = ((c * 4 + quad) ^ (l15 & 7)) * 8;   // swizzled read slot
    bfrag8 af[4], bq[4];
#pragma unroll
    for (int i = 0; i < 4; ++i)
      af[i] = *(const bfrag8*)(sA + (mrow + 16 * i + l15) * 64 + slot);
#pragma unroll
    for (int j2 = 0; j2 < 4; ++j2)
      bq[j2] = *(const bfrag8*)(sB + (nrow + 16 * j2 + l15) * 64 + slot);
#pragma unroll
    for (int i = 0; i < 4; ++i)
#pragma unroll
      for (int j2 = 0; j2 < 4; ++j2)
        acc[i][j2] = __builtin_amdgcn_mfma_f32_16x16x32_bf16(af[i], bq[j2], acc[i][j2], 0, 0, 0);
  }
}

// gemm1 variant: grid (16,16,8); XCD swizzle — bz = j&7 so each batch pins to one
// XCD (Qb[b]+Kb[b] = 4 MB = one XCD L2); within XCD, by fastest.
__global__ __launch_bounds__(256) void gemm_qk(
    const unsigned short* __restrict__ A, int lda, long long astr,
    const unsigned short* __restrict__ Bm, int ldb, long long bstr,
    float* __restrict__ C, int ldc, long long cstr,
    int kdim, float scale) {
  const unsigned j = blockIdx.x + 16u * blockIdx.y + 256u * blockIdx.z;
  const unsigned bz = j & 7u;           // batch == XCD residue
  const unsigned q = j >> 3;            // [0,256)
  const unsigned by = q & 15u;          // m-tile
  const unsigned bx = q >> 4;           // n-tile [0,16)

  __shared__ unsigned short smA[2][128 * 64];
  __shared__ unsigned short smB[2][128 * 64];
  const int tid = threadIdx.x;
  const int wave = tid >> 6, lane = tid & 63;
  const int quad = lane >> 4, l15 = lane & 15;
  const unsigned short* Ab = A + (long long)bz * astr + (size_t)(by * 128) * lda;
  const unsigned short* Bb = Bm + (long long)bz * bstr + (size_t)(bx * 128) * ldb;
  const int mrow = 64 * (wave >> 1);
  const int nrow = 64 * (wave & 1);

  facc4 acc[4][4];
  const facc4 fzero = {0.f, 0.f, 0.f, 0.f};
#pragma unroll
  for (int i = 0; i < 4; ++i)
#pragma unroll
    for (int j2 = 0; j2 < 4; ++j2) acc[i][j2] = fzero;

  // prologue: stage k-tile 0 into buffer 0 (exposed once)
  stage64(Ab, lda, 0, tid, smA[0]);
  stage64(Bb, ldb, 0, tid, smB[0]);
  __syncthreads();

  // kdim is a multiple of 128 -> 2 k-tiles of 64 per trip, static buffers
  for (int k0 = 0; k0 < kdim; k0 += 128) {
    stage64(Ab, lda, k0 + 64, tid, smA[1]);
    stage64(Bb, ldb, k0 + 64, tid, smB[1]);
    mfma_step64(smA[0], smB[0], mrow, nrow, l15, quad, acc);
    __syncthreads();
    if (k0 + 128 < kdim) {
      stage64(Ab, lda, k0 + 128, tid, smA[0]);
      stage64(Bb, ldb, k0 + 128, tid, smB[0]);
    }
    mfma_step64(smA[1], smB[1], mrow, nrow, l15, quad, acc);
    __syncthreads();
  }

  float* Cb = C + (long long)bz * cstr;
  const int mg = by * 128 + mrow;
  const int ng = bx * 128 + nrow;
#pragma unroll
  for (int i = 0; i < 4; ++i)
#pragma unroll
    for (int j2 = 0; j2 < 4; ++j2)
#pragma unroll
      for (int r = 0; r < 4; ++r)
        Cb[(size_t)(mg + 16 * i + quad * 4 + r) * ldc + ng + 16 * j2 + l15] = acc[i][j2][r] * scale;
}

// gemm2 variant: grid (4,16,8); bz = j&7 (batch pins to XCD, VT[b] 2 MB in L2);
// within XCD, bx fastest so the 4 n-blocks sharing one 512 KB attn A-tile run
// back-to-back on the same XCD (A fetched from HBM once).
__global__ __launch_bounds__(256) void gemm_pv(
    const unsigned short* __restrict__ A, int lda, long long astr,
    const unsigned short* __restrict__ Bm, int ldb, long long bstr,
    float* __restrict__ C, int ldc, long long cstr,
    int kdim, float scale) {
  const unsigned j = blockIdx.x + 4u * blockIdx.y + 64u * blockIdx.z;
  const unsigned bz = j & 7u;           // batch == XCD residue
  const unsigned q = j >> 3;            // [0,64)
  const unsigned bx = q & 3u;           // n-tile (fastest)
  const unsigned by = q >> 2;           // m-tile [0,16)

  __shared__ unsigned short smA[2][128 * 64];
  __shared__ unsigned short smB[2][128 * 64];
  const int tid = threadIdx.x;
  const int wave = tid >> 6, lane = tid & 63;
  const int quad = lane >> 4, l15 = lane & 15;
  const unsigned short* Ab = A + (long long)bz * astr + (size_t)(by * 128) * lda;
  const unsigned short* Bb = Bm + (long long)bz * bstr + (size_t)(bx * 128) * ldb;
  const int mrow = 64 * (wave >> 1);
  const int nrow = 64 * (wave & 1);

  facc4 acc[4][4];
  const facc4 fzero = {0.f, 0.f, 0.f, 0.f};
#pragma unroll
  for (int i = 0; i < 4; ++i)
#pragma unroll
    for (int j2 = 0; j2 < 4; ++j2) acc[i][j2] = fzero;

  stage64(Ab, lda, 0, tid, smA[0]);
  stage64(Bb, ldb, 0, tid, smB[0]);
  __syncthreads();

  for (int k0 = 0; k0 < kdim; k0 += 128) {
    stage64(Ab, lda, k0 + 64, tid, smA[1]);
    stage64(Bb, ldb, k0 + 64, tid, smB[1]);
    mfma_step64(smA[0], smB[0], mrow, nrow, l15, quad, acc);
    __syncthreads();
    if (k0 + 128 < kdim) {
      stage64(Ab, lda, k0 + 128, tid, smA[0]);
      stage64(Bb, ldb, k0 + 128, tid, smB[0]);
    }
    mfma_step64(smA[1], smB[1], mrow, nrow, l15, quad, acc);
    __syncthreads();
  }

  float* Cb = C + (long long)bz * cstr;
  const int mg = by * 128 + mrow;
  const int ng = bx * 128 + nrow;
#pragma unroll
  for (int i = 0; i < 4; ++i)
#pragma unroll
    for (int j2 = 0; j2 < 4; ++j2)
#pragma unroll
      for (int r = 0; r < 4; ++r)
        Cb[(size_t)(mg + 16 * i + quad * 4 + r) * ldc + ng + 16 * j2 + l15] = acc[i][j2][r] * scale;
}

// ---------- 256-bin radix-select step (per-wave histogram already counted) ----------
// bins[256]: counts. Finds digit d* s.t. count(digit > d*) < krem <= count(digit >= d*).
// Returns d*; *krem_out = krem - count(digit > d*)  (rank within the d* bin).
// If no crossing exists (total count < krem), returns 0 with *krem_out = 0.
__device__ __forceinline__ unsigned sel256(const unsigned* bins, int lane,
                                           unsigned krem, unsigned* krem_out) {
  const uint4 b = *(const uint4*)(bins + lane * 4);
  const unsigned s = b.x + b.y + b.z + b.w;
  unsigned t = s;
#pragma unroll
  for (int off = 1; off < 64; off <<= 1) {
    unsigned u = (unsigned)__shfl_down((int)t, off);
    t += (lane + off < 64) ? u : 0u;
  }
  const unsigned texcl = t - s;           // suffix over lanes > lane
  const unsigned c3 = texcl + b.w;        // count(digit >= lane*4+3)
  const unsigned c2 = c3 + b.z;
  const unsigned c1 = c2 + b.y;
  const unsigned c0 = c1 + b.x;
  unsigned pack = 0;                      // nonzero in at most one lane
  if (c0 >= krem && c1 < krem)    pack = ((krem - c1) << 8) | (lane * 4 + 0);
  if (c1 >= krem && c2 < krem)    pack = ((krem - c2) << 8) | (lane * 4 + 1);
  if (c2 >= krem && c3 < krem)    pack = ((krem - c3) << 8) | (lane * 4 + 2);
  if (c3 >= krem && texcl < krem) pack = ((krem - texcl) << 8) | (lane * 4 + 3);
#pragma unroll
  for (int off = 1; off < 64; off <<= 1)
    pack |= (unsigned)__shfl_xor((int)pack, off);
  *krem_out = pack >> 8;
  return pack & 255u;
}

// ---------- per-row exact top-204 + softmax-of-sparse; one WAVE per row ----------
// R6 (proven, part of best build): quantile-digit select, losers not counted.
// Pass-1 digit t=(key>>16)-0xBF00 counts only t in [1,255]; scores < ~0.5
// can't be top-204 when >=204 elements have t>=1 (N(0,1): ~632). d1 in
// [1,254] pins the key's top 16 bits; 2 more 8-bit passes finish. Degenerate
// cases (d1==0 no-crossing, d1==255 clamp-top) -> full exact 4-pass radix
// fallback (wave-uniform, never taken for this data).
__global__ __launch_bounds__(256) void topk_softmax(float* __restrict__ scores) {
  __shared__ unsigned binsAll[4][256];    // 1KB per wave
  const int tid = threadIdx.x;
  const int wave = tid >> 6, lane = tid & 63;
  const long long row = (long long)blockIdx.x * 4 + wave;
  float* srow = scores + row * 2048;
  unsigned* bins = binsAll[wave];

  unsigned k[32];
#pragma unroll
  for (int c = 0; c < 4; ++c) {
    float4 a = *(const float4*)(srow + c * 512 + lane * 8);
    float4 b = *(const float4*)(srow + c * 512 + lane * 8 + 4);
    k[c * 8 + 0] = fkey(a.x); k[c * 8 + 1] = fkey(a.y);
    k[c * 8 + 2] = fkey(a.z); k[c * 8 + 3] = fkey(a.w);
    k[c * 8 + 4] = fkey(b.x); k[c * 8 + 5] = fkey(b.y);
    k[c * 8 + 6] = fkey(b.z); k[c * 8 + 7] = fkey(b.w);
  }

  // row max (for softmax shift m = max(max_score, 0))
  unsigned kmax = 0;
#pragma unroll
  for (int i = 0; i < 32; ++i) kmax = max(kmax, k[i]);
#pragma unroll
  for (int off = 1; off < 64; off <<= 1)
    kmax = max(kmax, (unsigned)__shfl_xor((int)kmax, off));
  const float m = fmaxf(keyfloat(kmax), 0.f);

  // ---- pass 1: quantile digit t = (key>>16) - 0xBF00; count only t in [1,255] ----
  {
    uint4 z; z.x = 0; z.y = 0; z.z = 0; z.w = 0;
    *(uint4*)(bins + lane * 4) = z;
  }
#pragma unroll
  for (int i = 0; i < 32; ++i) {
    const int t = (int)(k[i] >> 16) - 0xBF00;
    if (t >= 1) atomicAdd(&bins[min(t, 255)], 1u);
  }
  unsigned krem;
  const unsigned d1 = sel256(bins, lane, KTOP, &krem);

  unsigned tkey;
  if (d1 >= 1u && d1 <= 254u) {
    // common path: key's top 16 bits are exactly 0xBF00+d1 (unclamped digit)
    const unsigned top16 = 0xBF00u + d1;
    // ---- pass 2: bits[15:8] among class (key>>16)==top16 ----
    { uint4 z; z.x = 0; z.y = 0; z.z = 0; z.w = 0; *(uint4*)(bins + lane * 4) = z; }
#pragma unroll
    for (int i = 0; i < 32; ++i)
      if ((k[i] >> 16) == top16) atomicAdd(&bins[(k[i] >> 8) & 255u], 1u);
    const unsigned b1 = sel256(bins, lane, krem, &krem);
    const unsigned top24 = (top16 << 8) | b1;
    // ---- pass 3: bits[7:0] among class (key>>8)==top24 ----
    { uint4 z; z.x = 0; z.y = 0; z.z = 0; z.w = 0; *(uint4*)(bins + lane * 4) = z; }
#pragma unroll
    for (int i = 0; i < 32; ++i)
      if ((k[i] >> 8) == top24) atomicAdd(&bins[k[i] & 255u], 1u);
    const unsigned b0 = sel256(bins, lane, krem, &krem);
    tkey = (top24 << 8) | b0;
  } else {
    // fallback: full exact 4-pass 8-bit radix from scratch. Never taken here.
    krem = KTOP;
    unsigned prefix = 0, mmask = 0;
    for (int shift = 24; shift >= 0; shift -= 8) {
      { uint4 z; z.x = 0; z.y = 0; z.z = 0; z.w = 0; *(uint4*)(bins + lane * 4) = z; }
#pragma unroll
      for (int i = 0; i < 32; ++i)
        if ((k[i] & mmask) == prefix) atomicAdd(&bins[(k[i] >> shift) & 255u], 1u);
      const unsigned dig = sel256(bins, lane, krem, &krem);
      prefix |= dig << shift;
      mmask |= 0xFFu << shift;
    }
    tkey = prefix;
  }

  // tie-break: accept the krem lowest-index elements with key == tkey.
  // cut = global index of the last accepted tie.
  unsigned cut;
  {
    unsigned tiem = 0;
#pragma unroll
    for (int i = 0; i < 32; ++i)
      if (k[i] == tkey) tiem |= 1u << i;
    unsigned need = krem;
    for (;;) {
      unsigned myidx = 0xFFFFFFFFu;
      if (tiem) {
        int i = __ffs((int)tiem) - 1;       // lowest i = smallest global idx in lane
        myidx = ((unsigned)(i >> 3)) * 512u + (unsigned)lane * 8u + (unsigned)(i & 7);
      }
      unsigned minidx = myidx;
#pragma unroll
      for (int off = 1; off < 64; off <<= 1)
        minidx = min(minidx, (unsigned)__shfl_xor((int)minidx, off));
      if (--need == 0 || minidx == 0xFFFFFFFFu) { cut = minidx; break; }
      if (myidx == minidx) tiem &= tiem - 1; // consume in owning lane
    }
  }

  // weights: exp(s-m) if selected, exp(-m) otherwise; Z = sum of all weights
  const float eqw = __expf(keyfloat(tkey) - m);
  const float base = __expf(-m);
  float zsum = 0.f;
#pragma unroll
  for (int i = 0; i < 32; ++i) {
    const unsigned key = k[i];
    const unsigned idx = ((unsigned)(i >> 3)) * 512u + (unsigned)lane * 8u + (unsigned)(i & 7);
    float w;
    if (key > tkey) w = __expf(keyfloat(key) - m);
    else w = (key == tkey && idx <= cut) ? eqw : base;
    zsum += w;
    k[i] = __float_as_uint(w);              // stash unnormalized weight
  }
#pragma unroll
  for (int off = 1; off < 64; off <<= 1) zsum += __shfl_xor(zsum, off);
  const float invZ = 1.f / zsum;

  // attn row (bf16) reuses the front 4KB of this row's 8KB score slot
  unsigned short* arow = (unsigned short*)scores + row * 4096;
#pragma unroll
  for (int c = 0; c < 4; ++c) {
    union { unsigned short u[8]; int4 v4; } pk;
#pragma unroll
    for (int j = 0; j < 8; ++j)
      pk.u[j] = f2bf(__uint_as_float(k[c * 8 + j]) * invZ);
    *(int4*)(arow + c * 512 + lane * 8) = pk.v4;
  }
}

// ---------- launch ----------
// ws layout (bytes): Qb[0,16MB) Kb[16,32MB) VT[32,48MB) scores/attn[48,176MB)
extern "C" void kernel_launch(void* const* d_in, const int* in_sizes, int n_in,
                              void* d_out, int out_size, void* d_ws, size_t ws_size,
                              hipStream_t stream) {
  const float* Q = (const float*)d_in[0];
  const float* K = (const float*)d_in[1];
  const float* V = (const float*)d_in[2];
  float* out = (float*)d_out;
  char* ws = (char*)d_ws;
  unsigned short* Qb = (unsigned short*)(ws);
  unsigned short* Kb = (unsigned short*)(ws + ((size_t)16 << 20));
  unsigned short* VT = (unsigned short*)(ws + ((size_t)32 << 20));
  float* scores = (float*)(ws + ((size_t)48 << 20));

  const int nel = B_ * S_ * D_;  // 8388608
  cvt_qk<<<dim3(nel / 1024, 2), 256, 0, stream>>>(Q, K, Qb, Kb);
  transpose_v<<<dim3(D_ / 32, S_ / 32, B_), 256, 0, stream>>>(V, VT);
  // scores[b][q][k] = sum_d Q[q][d]*K[k][d] * scale ; score row pitch = 2048 f32
  gemm_qk<<<dim3(S_ / 128, S_ / 128, B_), 256, 0, stream>>>(
      Qb, D_, (long long)S_ * D_, Kb, D_, (long long)S_ * D_,
      scores, S_, (long long)S_ * S_, D_, QK_SCALE);
  topk_softmax<<<B_ * S_ / 4, 256, 0, stream>>>(scores);
  // out[b][q][d] = sum_k attn[q][k]*VT[d][k] ; attn row pitch = 4096 bf16 (8KB slots)
  gemm_pv<<<dim3(D_ / 128, S_ / 128, B_), 256, 0, stream>>>(
      (const unsigned short*)scores, 4096, (long long)S_ * 4096,
      VT, S_, (long long)D_ * S_, out, D_, (long long)S_ * D_, S_, 1.0f);
}